// Round 4
// baseline (157.699 us; speedup 1.0000x reference)
//
#include <hip/hip_runtime.h>
#include <cstdint>

typedef __bf16 bf16_t;
typedef bf16_t bf16x4 __attribute__((ext_vector_type(4)));
typedef bf16_t bf16x8 __attribute__((ext_vector_type(8)));
typedef float f32x4 __attribute__((ext_vector_type(4)));

#define GLD_LDS16(g, l)                                                        \
  __builtin_amdgcn_global_load_lds(                                            \
      (const __attribute__((address_space(1))) void*)(g),                      \
      (__attribute__((address_space(3))) void*)(l), 16, 0, 0)

#define LOG2E 1.44269504088896340736f

static __device__ __forceinline__ unsigned short bf16_bits(float f) {
  bf16_t h = (bf16_t)f;
  return __builtin_bit_cast(unsigned short, h);
}

// ---- fused prep: fp32->bf16 convert (x,y) + weight transpose-convert ------
// bid < 6144: convert 12M elems (x then y), 8 per thread.
// bid >= 6144: 32x32 transpose tiles of Wq/Wk/Wv/Wo -> WqT/WkvT/WoT.
__global__ void prep_kernel(const float* __restrict__ x,
                            const float* __restrict__ y,
                            const float* __restrict__ Wq,
                            const float* __restrict__ Wk,
                            const float* __restrict__ Wv,
                            const float* __restrict__ Wo,
                            bf16_t* __restrict__ xb, bf16_t* __restrict__ yb,
                            bf16_t* __restrict__ WqT,
                            bf16_t* __restrict__ WkvT,
                            bf16_t* __restrict__ WoT) {
  __shared__ float tile[32][33];
  int bid = blockIdx.x;
  if (bid < 6144) {
    int i = bid * 256 + threadIdx.x;
    const float* src;
    bf16_t* dst;
    if (i < 524288) { src = x; dst = xb; }
    else            { src = y; dst = yb; i -= 524288; }
    const float4* s = (const float4*)src;
    float4 a = s[i * 2];
    float4 b = s[i * 2 + 1];
    bf16x8 o;
    o[0] = (bf16_t)a.x; o[1] = (bf16_t)a.y; o[2] = (bf16_t)a.z; o[3] = (bf16_t)a.w;
    o[4] = (bf16_t)b.x; o[5] = (bf16_t)b.y; o[6] = (bf16_t)b.z; o[7] = (bf16_t)b.w;
    *(bf16x8*)(dst + (size_t)i * 8) = o;
    return;
  }
  bid -= 6144;
  const float* src; bf16_t* dst; int R, lb;
  if (bid < 1024)      { src = Wq; dst = WqT;                        R = 1024; lb = bid; }
  else if (bid < 3072) { src = Wk; dst = WkvT;                       R = 2048; lb = bid - 1024; }
  else if (bid < 5120) { src = Wv; dst = WkvT + (size_t)1024 * 2048; R = 2048; lb = bid - 3072; }
  else                 { src = Wo; dst = WoT;                        R = 1024; lb = bid - 5120; }
  int c0 = (lb & 31) << 5, r0 = (lb >> 5) << 5;
  int tc = threadIdx.x & 31, tr = threadIdx.x >> 5;  // tr in 0..7
#pragma unroll
  for (int i = 0; i < 4; i++)
    tile[tr + i * 8][tc] = src[(size_t)(r0 + tr + i * 8) * 1024 + c0 + tc];
  __syncthreads();
#pragma unroll
  for (int i = 0; i < 4; i++)
    dst[(size_t)(c0 + tr + i * 8) * R + r0 + tc] = (bf16_t)tile[tc][tr + i * 8];
}

// ---------------- 128x128x32 bf16 GEMM, C = A * BT^T (both K-inner) --------
// m97 geometry (4 waves 2x2, 4x4 frags/wave, 16 MFMA : 8 ds_read_b128 per kt)
// + double-buffered single-barrier prefetch + A-panel-per-XCD swizzle.
// MODE 0: bf16 C (scaled); MODE 2: fp32 C; MODE 3: n0<1024 -> bf16 K,
// n0>=1024 -> bf16 V^T to Cp2.
template <int MODE>
__global__ __launch_bounds__(256, 2) void gemm_bt(
    const bf16_t* __restrict__ A0, const bf16_t* __restrict__ A1, int lda,
    int Ksplit, const bf16_t* __restrict__ BT, int Ktot,
    void* __restrict__ Cp, void* __restrict__ Cp2, int ldc, float scale) {
  __shared__ bf16_t As[2][128 * 32];
  __shared__ bf16_t Bs[2][128 * 32];
  const int t = threadIdx.x, w = t >> 6, l = t & 63;
  const int l15 = l & 15, l4 = l >> 4;
  const int wr = w >> 1, wc = w & 1;
  const int i = blockIdx.x;
  const int yb = (i & 7) * 4 + ((i >> 3) & 3);  // m-tile: same XCD per panel
  const int xb = i >> 5;                        // n-tile
  const int m0 = yb * 128, n0 = xb * 128;
  f32x4 acc[4][4] = {};
  const int nkt = Ktot >> 5;
  const int c0 = t, c1 = t + 256;  // A chunks; same ids for B
  const int ar0 = c0 >> 2, ak0 = (c0 & 3) * 8;
  const int ar1 = c1 >> 2, ak1 = (c1 & 3) * 8;

#define GEMM_STAGE(buf, kt)                                                    \
  {                                                                            \
    const int kbase = (kt) * 32;                                               \
    int kg0 = kbase + ak0;                                                     \
    const bf16_t* s0 = (kg0 < Ksplit)                                          \
                           ? (A0 + (size_t)(m0 + ar0) * lda + kg0)             \
                           : (A1 + (size_t)(m0 + ar0) * lda + (kg0 - Ksplit)); \
    GLD_LDS16(s0, As[buf] + c0 * 8);                                           \
    int kg1 = kbase + ak1;                                                     \
    const bf16_t* s1 = (kg1 < Ksplit)                                          \
                           ? (A0 + (size_t)(m0 + ar1) * lda + kg1)             \
                           : (A1 + (size_t)(m0 + ar1) * lda + (kg1 - Ksplit)); \
    GLD_LDS16(s1, As[buf] + c1 * 8);                                           \
    const bf16_t* b0 = BT + (size_t)(n0 + ar0) * Ktot + kbase + ak0;           \
    GLD_LDS16(b0, Bs[buf] + c0 * 8);                                           \
    const bf16_t* b1 = BT + (size_t)(n0 + ar1) * Ktot + kbase + ak1;           \
    GLD_LDS16(b1, Bs[buf] + c1 * 8);                                           \
  }

  GEMM_STAGE(0, 0);
  __syncthreads();
  int cur = 0;
  for (int kt = 0; kt < nkt; ++kt) {
    if (kt + 1 < nkt) GEMM_STAGE(cur ^ 1, kt + 1);
    bf16x8 af[4], bfr[4];
#pragma unroll
    for (int mi = 0; mi < 4; mi++)
      af[mi] = *(const bf16x8*)&As[cur][(wr * 64 + mi * 16 + l15) * 32 + l4 * 8];
#pragma unroll
    for (int ni = 0; ni < 4; ni++)
      bfr[ni] = *(const bf16x8*)&Bs[cur][(wc * 64 + ni * 16 + l15) * 32 + l4 * 8];
#pragma unroll
    for (int mi = 0; mi < 4; mi++)
#pragma unroll
      for (int ni = 0; ni < 4; ni++)
        acc[mi][ni] = __builtin_amdgcn_mfma_f32_16x16x32_bf16(
            af[mi], bfr[ni], acc[mi][ni], 0, 0, 0);
    __syncthreads();
    cur ^= 1;
  }

#pragma unroll
  for (int mi = 0; mi < 4; mi++) {
#pragma unroll
    for (int ni = 0; ni < 4; ni++) {
      const int rbase = m0 + wr * 64 + mi * 16 + l4 * 4;
      const int col = n0 + wc * 64 + ni * 16 + l15;
      if (MODE == 0) {
        bf16_t* C = (bf16_t*)Cp;
#pragma unroll
        for (int rr = 0; rr < 4; rr++)
          C[(size_t)(rbase + rr) * ldc + col] =
              (bf16_t)(acc[mi][ni][rr] * scale);
      } else if (MODE == 2) {
        float* C = (float*)Cp;
#pragma unroll
        for (int rr = 0; rr < 4; rr++)
          C[(size_t)(rbase + rr) * ldc + col] = acc[mi][ni][rr];
      } else {  // MODE 3: K normal / V transposed (block-uniform branch)
        if (n0 < 1024) {
          bf16_t* C = (bf16_t*)Cp;
#pragma unroll
          for (int rr = 0; rr < 4; rr++)
            C[(size_t)(rbase + rr) * ldc + col] = (bf16_t)acc[mi][ni][rr];
        } else {
          bf16_t* VT = (bf16_t*)Cp2;
          union { unsigned short u[4]; uint2 v; } pk;
#pragma unroll
          for (int rr = 0; rr < 4; rr++)
            pk.u[rr] = bf16_bits(acc[mi][ni][rr]);
          *(uint2*)&VT[(size_t)(col - 1024) * 4096 + rbase] = pk.v;
        }
      }
    }
  }
#undef GEMM_STAGE
}

// ---------------- flash attention, swapped-softmax --------------------------
// QB=64 (4 waves x 16 q), KB=64. S^T = mfma(K,Q): key-reduction is
// register-local (15 fmax + 2 shfl). P^T -> per-wave LDS [key_hi][q][key_lo],
// PV = mfma(V^T, P^T). exp2-domain (log2e pre-folded into Q and bias).
__global__ __launch_bounds__(256, 4) void attn_kernel(
    const bf16_t* __restrict__ Q, const bf16_t* __restrict__ K,
    const bf16_t* __restrict__ VT, const float* __restrict__ bias,
    bf16_t* __restrict__ ctx) {
  __shared__ bf16_t Ks[2][64 * 64];
  __shared__ bf16_t Vs[2][64 * 64];
  __shared__ bf16_t Ps[4][1024];  // per-wave P^T: [khi(8)][q(16)][klo(8)]
  const int t = threadIdx.x, w = t >> 6, l = t & 63;
  const int l15 = l & 15, l4 = l >> 4;
  const int id = blockIdx.x;
  const int bh = id & 63, qt = id >> 6;
  const int b = bh >> 4, h = bh & 15;

  // Q as B-operand: col=q=w*16+l15, inner d = ks*32+l4*8+j
  bf16x8 qf[2];
  {
    const bf16_t* Qb =
        Q + (size_t)(b * 1024 + qt * 64 + w * 16 + l15) * 1024 + h * 64;
#pragma unroll
    for (int ks = 0; ks < 2; ks++)
      qf[ks] = *(const bf16x8*)&Qb[ks * 32 + l4 * 8];
  }

#define ATTN_STAGE(buf, kt)                                                    \
  {                                                                            \
    _Pragma("unroll") for (int j = 0; j < 2; j++) {                            \
      int c = t + j * 256;                                                     \
      int row = c >> 3, sl = (c & 7) ^ (row & 7);                              \
      const bf16_t* srck =                                                     \
          K + (size_t)(b * 1024 + (kt) * 64 + row) * 1024 + h * 64 + sl * 8;   \
      GLD_LDS16(srck, Ks[buf] + c * 8);                                        \
      const bf16_t* srcv =                                                     \
          VT + (size_t)(h * 64 + row) * 4096 + b * 1024 + (kt) * 64 + sl * 8;  \
      GLD_LDS16(srcv, Vs[buf] + c * 8);                                        \
    }                                                                          \
  }

  float mrun = -INFINITY, lrun = 0.f;
  f32x4 ctxacc[4] = {};  // ctx^T: d=ni*16+l4*4+rr, q=w*16+l15

  ATTN_STAGE(0, 0);
  __syncthreads();
  int cur = 0;
  for (int kt = 0; kt < 16; ++kt) {
    if (kt + 1 < 16) ATTN_STAGE(cur ^ 1, kt + 1);

    // S^T: sacc[ni] holds keys ni*16+l4*4+rr for q=l15 (wave-local)
    f32x4 sacc[4] = {};
#pragma unroll
    for (int ks = 0; ks < 2; ks++) {
#pragma unroll
      for (int ni = 0; ni < 4; ni++) {
        int krow = ni * 16 + l15;
        int eoff = (krow * 64 + ks * 32 + l4 * 8) ^ ((krow & 7) << 3);
        bf16x8 kf = *(const bf16x8*)&Ks[cur][eoff];
        sacc[ni] = __builtin_amdgcn_mfma_f32_16x16x32_bf16(kf, qf[ks],
                                                           sacc[ni], 0, 0, 0);
      }
    }
    // + bias*2*log2e (per key = row of S^T): contiguous float4 per ni
#pragma unroll
    for (int ni = 0; ni < 4; ni++) {
      float4 bb =
          *(const float4*)&bias[b * 1024 + kt * 64 + ni * 16 + l4 * 4];
      sacc[ni][0] += (2.0f * LOG2E) * bb.x;
      sacc[ni][1] += (2.0f * LOG2E) * bb.y;
      sacc[ni][2] += (2.0f * LOG2E) * bb.z;
      sacc[ni][3] += (2.0f * LOG2E) * bb.w;
    }
    // softmax (base 2), register-local over 16 values + 2 shuffles
    float tm = -INFINITY;
#pragma unroll
    for (int ni = 0; ni < 4; ni++)
#pragma unroll
      for (int rr = 0; rr < 4; rr++) tm = fmaxf(tm, sacc[ni][rr]);
    tm = fmaxf(tm, __shfl_xor(tm, 16));
    tm = fmaxf(tm, __shfl_xor(tm, 32));
    float mnew = fmaxf(mrun, tm);
    float sc = exp2f(mrun - mnew);
    float rsum = 0.f;
#pragma unroll
    for (int ni = 0; ni < 4; ni++) {
      bf16x4 pk;
#pragma unroll
      for (int rr = 0; rr < 4; rr++) {
        float p = exp2f(sacc[ni][rr] - mnew);
        rsum += p;
        pk[rr] = (bf16_t)p;
      }
      // key = ni*16 + l4*4 + rr -> khi = ni*2+(l4>>1), klo = (l4&1)*4+rr
      *(bf16x4*)&Ps[w][(ni * 2 + (l4 >> 1)) * 128 + l15 * 8 + (l4 & 1) * 4] =
          pk;
    }
    rsum += __shfl_xor(rsum, 16);
    rsum += __shfl_xor(rsum, 32);
    lrun = lrun * sc + rsum;
    mrun = mnew;
#pragma unroll
    for (int ni = 0; ni < 4; ni++) ctxacc[ni] *= sc;
    // PV: ctx^T = mfma(A=V^T[d][key], B=P^T[key][q])
#pragma unroll
    for (int kk = 0; kk < 2; kk++) {
      bf16x8 pf = *(const bf16x8*)&Ps[w][(kk * 4 + l4) * 128 + l15 * 8];
#pragma unroll
      for (int ni = 0; ni < 4; ni++) {
        int drow = ni * 16 + l15;
        int voff = (drow * 64 + kk * 32 + l4 * 8) ^ ((drow & 7) << 3);
        bf16x8 vf = *(const bf16x8*)&Vs[cur][voff];
        ctxacc[ni] = __builtin_amdgcn_mfma_f32_16x16x32_bf16(vf, pf, ctxacc[ni],
                                                             0, 0, 0);
      }
    }
    __syncthreads();
    cur ^= 1;
  }

  // epilogue: ctx^T -> LDS transpose (swizzled) -> coalesced bf16x8 stores
  bf16_t* T = Ks[0];  // 64q x 64d
  {
    float inv = 1.0f / lrun;
    int q = w * 16 + l15;
#pragma unroll
    for (int ni = 0; ni < 4; ni++) {
      bf16x4 tv;
#pragma unroll
      for (int rr = 0; rr < 4; rr++) tv[rr] = (bf16_t)(ctxacc[ni][rr] * inv);
      int d0 = ni * 16 + l4 * 4;
      *(bf16x4*)&T[q * 64 + (d0 ^ ((l15 & 7) << 3))] = tv;
    }
  }
  __syncthreads();
#pragma unroll
  for (int c = t; c < 512; c += 256) {
    int row = c >> 3, col8 = c & 7;
    bf16x8 v = *(const bf16x8*)&T[row * 64 + ((col8 * 8) ^ ((row & 7) << 3))];
    *(bf16x8*)&ctx[(size_t)(b * 1024 + qt * 64 + row) * 1024 + h * 64 +
                   col8 * 8] = v;
  }
#undef ATTN_STAGE
}

extern "C" void kernel_launch(void* const* d_in, const int* in_sizes, int n_in,
                              void* d_out, int out_size, void* d_ws,
                              size_t ws_size, hipStream_t stream) {
  const float* x = (const float*)d_in[0];    // [4,1024,1024]
  const float* y = (const float*)d_in[1];    // [2,4,1024,1024]
  const float* bias = (const float*)d_in[2]; // [4,1,1,1024]
  const float* Wq = (const float*)d_in[3];   // [1024,1024]
  const float* Wk = (const float*)d_in[4];   // [2,1024,1024]
  const float* Wv = (const float*)d_in[5];
  const float* Wo = (const float*)d_in[6];
  float* out = (float*)d_out;                // [4,1024,1024] fp32

  char* ws = (char*)d_ws;
  const size_t MB = 1024 * 1024;
  bf16_t* xb   = (bf16_t*)(ws + 0 * MB);    // 8MB
  bf16_t* yb   = (bf16_t*)(ws + 8 * MB);    // 16MB
  bf16_t* WqT  = (bf16_t*)(ws + 24 * MB);   // 2MB
  bf16_t* WkvT = (bf16_t*)(ws + 26 * MB);   // 8MB  [2048 n][2048 k]
  bf16_t* WoT  = (bf16_t*)(ws + 34 * MB);   // 2MB
  bf16_t* Qb   = (bf16_t*)(ws + 36 * MB);   // 8MB  (pre-scaled by d^-.5*log2e)
  bf16_t* Kb   = (bf16_t*)(ws + 44 * MB);   // 8MB
  bf16_t* VTb  = (bf16_t*)(ws + 52 * MB);   // 8MB  [1024 d][4096 q]
  bf16_t* ctxb = (bf16_t*)(ws + 60 * MB);   // 8MB

  prep_kernel<<<12288, 256, 0, stream>>>(x, y, Wq, Wk, Wv, Wo, xb, yb, WqT,
                                         WkvT, WoT);

  // Q = (x Wq) * d^-0.5 * log2e          [4096,1024], 256 blocks
  gemm_bt<0><<<256, 256, 0, stream>>>(xb, xb, 1024, 1024, WqT, 1024, Qb,
                                      nullptr, 1024, 0.125f * LOG2E);
  // K = sum_l y_l Wk_l ; V^T = (sum_l y_l Wv_l)^T   (fused, N=2048), 512 blk
  gemm_bt<3><<<512, 256, 0, stream>>>(yb, yb + (size_t)4096 * 1024, 1024, 1024,
                                      WkvT, 2048, Kb, VTb, 1024, 1.0f);
  attn_kernel<<<1024, 256, 0, stream>>>(Qb, Kb, VTb, bias, ctxb);
  // out = ctx Wo (fp32), 256 blocks
  gemm_bt<2><<<256, 256, 0, stream>>>(ctxb, ctxb, 1024, 1024, WoT, 1024, out,
                                      nullptr, 1024, 1.0f);
}

// Round 5
// 137.777 us; speedup vs baseline: 1.1446x; 1.1446x over previous
//
#include <hip/hip_runtime.h>
#include <cstdint>

typedef __bf16 bf16_t;
typedef bf16_t bf16x4 __attribute__((ext_vector_type(4)));
typedef bf16_t bf16x8 __attribute__((ext_vector_type(8)));
typedef float f32x4 __attribute__((ext_vector_type(4)));

#define GLD_LDS16(g, l)                                                        \
  __builtin_amdgcn_global_load_lds(                                            \
      (const __attribute__((address_space(1))) void*)(g),                      \
      (__attribute__((address_space(3))) void*)(l), 16, 0, 0)

#define LOG2E 1.44269504088896340736f

static __device__ __forceinline__ unsigned short bf16_bits(float f) {
  bf16_t h = (bf16_t)f;
  return __builtin_bit_cast(unsigned short, h);
}

// ---- fused prep: fp32->bf16 convert (x,y) + weight transpose-convert ------
__global__ void prep_kernel(const float* __restrict__ x,
                            const float* __restrict__ y,
                            const float* __restrict__ Wq,
                            const float* __restrict__ Wk,
                            const float* __restrict__ Wv,
                            const float* __restrict__ Wo,
                            bf16_t* __restrict__ xb, bf16_t* __restrict__ yb,
                            bf16_t* __restrict__ WqT,
                            bf16_t* __restrict__ WkvT,
                            bf16_t* __restrict__ WoT) {
  __shared__ float tile[32][33];
  int bid = blockIdx.x;
  if (bid < 6144) {
    int i = bid * 256 + threadIdx.x;
    const float* src;
    bf16_t* dst;
    if (i < 524288) { src = x; dst = xb; }
    else            { src = y; dst = yb; i -= 524288; }
    const float4* s = (const float4*)src;
    float4 a = s[i * 2];
    float4 b = s[i * 2 + 1];
    bf16x8 o;
    o[0] = (bf16_t)a.x; o[1] = (bf16_t)a.y; o[2] = (bf16_t)a.z; o[3] = (bf16_t)a.w;
    o[4] = (bf16_t)b.x; o[5] = (bf16_t)b.y; o[6] = (bf16_t)b.z; o[7] = (bf16_t)b.w;
    *(bf16x8*)(dst + (size_t)i * 8) = o;
    return;
  }
  bid -= 6144;
  const float* src; bf16_t* dst; int R, lb;
  if (bid < 1024)      { src = Wq; dst = WqT;                        R = 1024; lb = bid; }
  else if (bid < 3072) { src = Wk; dst = WkvT;                       R = 2048; lb = bid - 1024; }
  else if (bid < 5120) { src = Wv; dst = WkvT + (size_t)1024 * 2048; R = 2048; lb = bid - 3072; }
  else                 { src = Wo; dst = WoT;                        R = 1024; lb = bid - 5120; }
  int c0 = (lb & 31) << 5, r0 = (lb >> 5) << 5;
  int tc = threadIdx.x & 31, tr = threadIdx.x >> 5;  // tr in 0..7
#pragma unroll
  for (int i = 0; i < 4; i++)
    tile[tr + i * 8][tc] = src[(size_t)(r0 + tr + i * 8) * 1024 + c0 + tc];
  __syncthreads();
#pragma unroll
  for (int i = 0; i < 4; i++)
    dst[(size_t)(c0 + tr + i * 8) * R + r0 + tc] = (bf16_t)tile[tc][tr + i * 8];
}

// ============ shared GEMM body pieces (128x128x32, 4 waves 2x2) ============
// LDS slot swizzle: within a 64B row (4 x 16B slots), slot s holds global
// slot s ^ ((row>>1)&3). Staged with linear LDS dest + pre-swizzled global
// source; read back with the same XOR -> 2-way (free) bank access.

#define GEMM_STAGE(buf, kt)                                                    \
  {                                                                            \
    const int kbase = (kt) * 32;                                               \
    int kg0 = kbase + ak0;                                                     \
    const bf16_t* s0 = (kg0 < Ksplit)                                          \
                           ? (A0 + (size_t)(m0 + ar0) * 1024 + kg0)            \
                           : (A1 + (size_t)(m0 + ar0) * 1024 + (kg0 - Ksplit));\
    GLD_LDS16(s0, As[buf] + c0 * 8);                                           \
    int kg1 = kbase + ak1;                                                     \
    const bf16_t* s1 = (kg1 < Ksplit)                                          \
                           ? (A0 + (size_t)(m0 + ar1) * 1024 + kg1)            \
                           : (A1 + (size_t)(m0 + ar1) * 1024 + (kg1 - Ksplit));\
    GLD_LDS16(s1, As[buf] + c1 * 8);                                           \
    const bf16_t* b0 = BT + (size_t)(n0 + ar0) * Ktot + kbase + ak0;           \
    GLD_LDS16(b0, Bs[buf] + c0 * 8);                                           \
    const bf16_t* b1 = BT + (size_t)(n0 + ar1) * Ktot + kbase + ak1;           \
    GLD_LDS16(b1, Bs[buf] + c1 * 8);                                           \
  }

#define GEMM_DECLS                                                             \
  const int t = threadIdx.x, w = t >> 6, l = t & 63;                           \
  const int l15 = l & 15, l4 = l >> 4;                                         \
  const int wr = w >> 1, wc = w & 1;                                           \
  const int c0 = t, c1 = t + 256;                                              \
  const int ar0 = c0 >> 2, ar1 = c1 >> 2;                                      \
  const int ak0 = ((c0 & 3) ^ ((ar0 >> 1) & 3)) * 8;                           \
  const int ak1 = ((c1 & 3) ^ ((ar1 >> 1) & 3)) * 8;                           \
  int offA[4], offB[4];                                                        \
  _Pragma("unroll") for (int mi = 0; mi < 4; mi++) {                           \
    int rA = wr * 64 + mi * 16 + l15;                                          \
    offA[mi] = rA * 32 + (l4 ^ ((rA >> 1) & 3)) * 8;                           \
    int rB = wc * 64 + mi * 16 + l15;                                          \
    offB[mi] = rB * 32 + (l4 ^ ((rB >> 1) & 3)) * 8;                           \
  }

#define GEMM_MAINLOOP                                                          \
  GEMM_STAGE(0, 0);                                                            \
  __syncthreads();                                                             \
  int cur = 0;                                                                 \
  for (int kt = 0; kt < nkt; ++kt) {                                           \
    if (kt + 1 < nkt) GEMM_STAGE(cur ^ 1, kt + 1);                             \
    bf16x8 af[4], bfr[4];                                                      \
    _Pragma("unroll") for (int mi = 0; mi < 4; mi++)                           \
        af[mi] = *(const bf16x8*)&As[cur][offA[mi]];                           \
    _Pragma("unroll") for (int ni = 0; ni < 4; ni++)                           \
        bfr[ni] = *(const bf16x8*)&Bs[cur][offB[ni]];                          \
    _Pragma("unroll") for (int mi = 0; mi < 4; mi++)                           \
        _Pragma("unroll") for (int ni = 0; ni < 4; ni++)                       \
            acc[mi][ni] = __builtin_amdgcn_mfma_f32_16x16x32_bf16(             \
                af[mi], bfr[ni], acc[mi][ni], 0, 0, 0);                        \
    __syncthreads();                                                           \
    cur ^= 1;                                                                  \
  }

// ---- fused Q-proj + KV-proj: blocks 0..255 -> Q (K=1024); 256..767 -> KV --
__global__ __launch_bounds__(256, 2) void qkv_kernel(
    const bf16_t* __restrict__ xbp, const bf16_t* __restrict__ ybp,
    const bf16_t* __restrict__ WqT, const bf16_t* __restrict__ WkvT,
    bf16_t* __restrict__ Qb, bf16_t* __restrict__ Kb,
    bf16_t* __restrict__ VTb) {
  __shared__ bf16_t As[2][128 * 32];
  __shared__ bf16_t Bs[2][128 * 32];
  GEMM_DECLS
  const bool isQ = blockIdx.x < 256;
  const int i = isQ ? blockIdx.x : blockIdx.x - 256;
  const int ybt = (i & 7) * 4 + ((i >> 3) & 3);  // A-panel per XCD
  const int xbt = i >> 5;
  const int m0 = ybt * 128, n0 = xbt * 128;
  const bf16_t* A0 = isQ ? xbp : ybp;
  const bf16_t* A1 = isQ ? xbp : ybp + (size_t)4096 * 1024;
  const int Ksplit = 1024;
  const bf16_t* BT = isQ ? WqT : WkvT;
  const int Ktot = isQ ? 1024 : 2048;
  const int nkt = Ktot >> 5;
  f32x4 acc[4][4] = {};

  GEMM_MAINLOOP

#pragma unroll
  for (int mi = 0; mi < 4; mi++) {
#pragma unroll
    for (int ni = 0; ni < 4; ni++) {
      const int rbase = m0 + wr * 64 + mi * 16 + l4 * 4;
      const int col = n0 + wc * 64 + ni * 16 + l15;
      if (isQ) {
#pragma unroll
        for (int rr = 0; rr < 4; rr++)
          Qb[(size_t)(rbase + rr) * 1024 + col] =
              (bf16_t)(acc[mi][ni][rr] * (0.125f * LOG2E));
      } else if (n0 < 1024) {
#pragma unroll
        for (int rr = 0; rr < 4; rr++)
          Kb[(size_t)(rbase + rr) * 1024 + col] = (bf16_t)acc[mi][ni][rr];
      } else {
        union { unsigned short u[4]; uint2 v; } pk;
#pragma unroll
        for (int rr = 0; rr < 4; rr++)
          pk.u[rr] = bf16_bits(acc[mi][ni][rr]);
        *(uint2*)&VTb[(size_t)(col - 1024) * 4096 + rbase] = pk.v;
      }
    }
  }
}

// ---- O-proj: out(fp32) = ctx * WoT^T ---------------------------------------
__global__ __launch_bounds__(256, 2) void gemm_o(const bf16_t* __restrict__ A0,
                                                 const bf16_t* __restrict__ BT,
                                                 float* __restrict__ Cp) {
  __shared__ bf16_t As[2][128 * 32];
  __shared__ bf16_t Bs[2][128 * 32];
  GEMM_DECLS
  const int i = blockIdx.x;
  const int ybt = (i & 7) * 4 + ((i >> 3) & 3);
  const int xbt = i >> 5;
  const int m0 = ybt * 128, n0 = xbt * 128;
  const bf16_t* A1 = A0;
  const int Ksplit = 1024, Ktot = 1024, nkt = 32;
  f32x4 acc[4][4] = {};

  GEMM_MAINLOOP

#pragma unroll
  for (int mi = 0; mi < 4; mi++) {
#pragma unroll
    for (int ni = 0; ni < 4; ni++) {
      const int rbase = m0 + wr * 64 + mi * 16 + l4 * 4;
      const int col = n0 + wc * 64 + ni * 16 + l15;
#pragma unroll
      for (int rr = 0; rr < 4; rr++)
        Cp[(size_t)(rbase + rr) * 1024 + col] = acc[mi][ni][rr];
    }
  }
}

// ---------------- flash attention, swapped-softmax --------------------------
__global__ __launch_bounds__(256, 4) void attn_kernel(
    const bf16_t* __restrict__ Q, const bf16_t* __restrict__ K,
    const bf16_t* __restrict__ VT, const float* __restrict__ bias,
    bf16_t* __restrict__ ctx) {
  __shared__ bf16_t Ks[2][64 * 64];
  __shared__ bf16_t Vs[2][64 * 64];
  __shared__ bf16_t Ps[4][1024];  // per-wave P^T: [khi(8)][q(16)][klo(8)]
  const int t = threadIdx.x, w = t >> 6, l = t & 63;
  const int l15 = l & 15, l4 = l >> 4;
  const int id = blockIdx.x;
  const int bh = id & 63, qt = id >> 6;
  const int b = bh >> 4, h = bh & 15;

  bf16x8 qf[2];
  {
    const bf16_t* Qb =
        Q + (size_t)(b * 1024 + qt * 64 + w * 16 + l15) * 1024 + h * 64;
#pragma unroll
    for (int ks = 0; ks < 2; ks++)
      qf[ks] = *(const bf16x8*)&Qb[ks * 32 + l4 * 8];
  }

#define ATTN_STAGE(buf, kt)                                                    \
  {                                                                            \
    _Pragma("unroll") for (int j = 0; j < 2; j++) {                            \
      int c = t + j * 256;                                                     \
      int row = c >> 3, sl = (c & 7) ^ (row & 7);                              \
      const bf16_t* srck =                                                     \
          K + (size_t)(b * 1024 + (kt) * 64 + row) * 1024 + h * 64 + sl * 8;   \
      GLD_LDS16(srck, Ks[buf] + c * 8);                                        \
      const bf16_t* srcv =                                                     \
          VT + (size_t)(h * 64 + row) * 4096 + b * 1024 + (kt) * 64 + sl * 8;  \
      GLD_LDS16(srcv, Vs[buf] + c * 8);                                        \
    }                                                                          \
  }

  float mrun = -INFINITY, lrun = 0.f;
  f32x4 ctxacc[4] = {};  // ctx^T: d=ni*16+l4*4+rr, q=w*16+l15

  ATTN_STAGE(0, 0);
  __syncthreads();
  int cur = 0;
  for (int kt = 0; kt < 16; ++kt) {
    if (kt + 1 < 16) ATTN_STAGE(cur ^ 1, kt + 1);

    f32x4 sacc[4] = {};
#pragma unroll
    for (int ks = 0; ks < 2; ks++) {
#pragma unroll
      for (int ni = 0; ni < 4; ni++) {
        int krow = ni * 16 + l15;
        int eoff = (krow * 64 + ks * 32 + l4 * 8) ^ ((krow & 7) << 3);
        bf16x8 kf = *(const bf16x8*)&Ks[cur][eoff];
        sacc[ni] = __builtin_amdgcn_mfma_f32_16x16x32_bf16(kf, qf[ks],
                                                           sacc[ni], 0, 0, 0);
      }
    }
#pragma unroll
    for (int ni = 0; ni < 4; ni++) {
      float4 bb =
          *(const float4*)&bias[b * 1024 + kt * 64 + ni * 16 + l4 * 4];
      sacc[ni][0] += (2.0f * LOG2E) * bb.x;
      sacc[ni][1] += (2.0f * LOG2E) * bb.y;
      sacc[ni][2] += (2.0f * LOG2E) * bb.z;
      sacc[ni][3] += (2.0f * LOG2E) * bb.w;
    }
    float tm = -INFINITY;
#pragma unroll
    for (int ni = 0; ni < 4; ni++)
#pragma unroll
      for (int rr = 0; rr < 4; rr++) tm = fmaxf(tm, sacc[ni][rr]);
    tm = fmaxf(tm, __shfl_xor(tm, 16));
    tm = fmaxf(tm, __shfl_xor(tm, 32));
    float mnew = fmaxf(mrun, tm);
    float sc = exp2f(mrun - mnew);
    float rsum = 0.f;
#pragma unroll
    for (int ni = 0; ni < 4; ni++) {
      bf16x4 pk;
#pragma unroll
      for (int rr = 0; rr < 4; rr++) {
        float p = exp2f(sacc[ni][rr] - mnew);
        rsum += p;
        pk[rr] = (bf16_t)p;
      }
      *(bf16x4*)&Ps[w][(ni * 2 + (l4 >> 1)) * 128 + l15 * 8 + (l4 & 1) * 4] =
          pk;
    }
    rsum += __shfl_xor(rsum, 16);
    rsum += __shfl_xor(rsum, 32);
    lrun = lrun * sc + rsum;
    mrun = mnew;
#pragma unroll
    for (int ni = 0; ni < 4; ni++) ctxacc[ni] *= sc;
#pragma unroll
    for (int kk = 0; kk < 2; kk++) {
      bf16x8 pf = *(const bf16x8*)&Ps[w][(kk * 4 + l4) * 128 + l15 * 8];
#pragma unroll
      for (int ni = 0; ni < 4; ni++) {
        int drow = ni * 16 + l15;
        int voff = (drow * 64 + kk * 32 + l4 * 8) ^ ((drow & 7) << 3);
        bf16x8 vf = *(const bf16x8*)&Vs[cur][voff];
        ctxacc[ni] = __builtin_amdgcn_mfma_f32_16x16x32_bf16(vf, pf, ctxacc[ni],
                                                             0, 0, 0);
      }
    }
    __syncthreads();
    cur ^= 1;
  }

  // epilogue: ctx^T -> LDS transpose (swizzled) -> coalesced bf16x8 stores
  bf16_t* T = Ks[0];  // 64q x 64d
  {
    float inv = 1.0f / lrun;
    int q = w * 16 + l15;
#pragma unroll
    for (int ni = 0; ni < 4; ni++) {
      bf16x4 tv;
#pragma unroll
      for (int rr = 0; rr < 4; rr++) tv[rr] = (bf16_t)(ctxacc[ni][rr] * inv);
      int d0 = ni * 16 + l4 * 4;
      *(bf16x4*)&T[q * 64 + (d0 ^ ((l15 & 7) << 3))] = tv;
    }
  }
  __syncthreads();
#pragma unroll
  for (int c = t; c < 512; c += 256) {
    int row = c >> 3, col8 = c & 7;
    bf16x8 v = *(const bf16x8*)&T[row * 64 + ((col8 * 8) ^ ((row & 7) << 3))];
    *(bf16x8*)&ctx[(size_t)(b * 1024 + qt * 64 + row) * 1024 + h * 64 +
                   col8 * 8] = v;
  }
#undef ATTN_STAGE
}

extern "C" void kernel_launch(void* const* d_in, const int* in_sizes, int n_in,
                              void* d_out, int out_size, void* d_ws,
                              size_t ws_size, hipStream_t stream) {
  const float* x = (const float*)d_in[0];    // [4,1024,1024]
  const float* y = (const float*)d_in[1];    // [2,4,1024,1024]
  const float* bias = (const float*)d_in[2]; // [4,1,1,1024]
  const float* Wq = (const float*)d_in[3];   // [1024,1024]
  const float* Wk = (const float*)d_in[4];   // [2,1024,1024]
  const float* Wv = (const float*)d_in[5];
  const float* Wo = (const float*)d_in[6];
  float* out = (float*)d_out;                // [4,1024,1024] fp32

  char* ws = (char*)d_ws;
  const size_t MB = 1024 * 1024;
  bf16_t* xb   = (bf16_t*)(ws + 0 * MB);    // 8MB
  bf16_t* yb   = (bf16_t*)(ws + 8 * MB);    // 16MB
  bf16_t* WqT  = (bf16_t*)(ws + 24 * MB);   // 2MB
  bf16_t* WkvT = (bf16_t*)(ws + 26 * MB);   // 8MB  [2048 n][2048 k]
  bf16_t* WoT  = (bf16_t*)(ws + 34 * MB);   // 2MB
  bf16_t* Qb   = (bf16_t*)(ws + 36 * MB);   // 8MB  (pre-scaled d^-.5*log2e)
  bf16_t* Kb   = (bf16_t*)(ws + 44 * MB);   // 8MB
  bf16_t* VTb  = (bf16_t*)(ws + 52 * MB);   // 8MB  [1024 d][4096 q]
  bf16_t* ctxb = (bf16_t*)(ws + 60 * MB);   // 8MB

  prep_kernel<<<12288, 256, 0, stream>>>(x, y, Wq, Wk, Wv, Wo, xb, yb, WqT,
                                         WkvT, WoT);
  // Q-proj (blocks 0..255) + KV-proj (blocks 256..767), fused
  qkv_kernel<<<768, 256, 0, stream>>>(xb, yb, WqT, WkvT, Qb, Kb, VTb);
  attn_kernel<<<1024, 256, 0, stream>>>(Qb, Kb, VTb, bias, ctxb);
  gemm_o<<<256, 256, 0, stream>>>(ctxb, WoT, out);
}